// Round 2
// baseline (109.701 us; speedup 1.0000x reference)
//
#include <hip/hip_runtime.h>
#include <math.h>

// Problem shape (fixed by setup_inputs): logits [8,12,256,256] fp32, targets [8,256,256] i32.
constexpr int B_  = 8;
constexpr int C_  = 12;
constexpr int H_  = 256;
constexpr int W_  = 256;
constexpr int HW_ = H_ * W_;
constexpr int NBC_ = B_ * C_;           // 96
constexpr int PAD_ = 256;               // LDS row padding (covers max radius 255)
constexpr int VB_  = NBC_ * 4;          // vert blocks (384): 64 columns per block
constexpr int SMB_ = B_ * (HW_ / 1024); // softmax-stats blocks (512, 4 px/thread)

// Packed vertical-EDT value: bit15 = is_fg (t==c); bits[14:0] = vertical
// distance d to nearest zero of the pixel's own nonzero transform
// (0x7FFF = no zero in column -> reference g = 1e6 - h). The OTHER
// transform's g is always 0 at this pixel, so one u16 encodes both.

// ---------------------------------------------------------------------------
// K1 (merged): blocks [0,384) = vertical EDT scans (64 cols x 8 segments,
// 2 adjacent columns per thread -> int2 loads, packed u32 stores = half the
// VMEM instructions of the 1-col variant); blocks [384, 384+512) = per-pixel
// softmax stats den = {max, 1/sum}, float4 (4 px/thread). Block 0 zeroes
// out[0] (consumed by k_bcred two dispatches later -- stream order).
// Intermediate forward-pass state is u8-packed (dl-1, 255=invalid) instead of
// two int[32] arrays -> ~32 fewer VGPRs, all indices compile-time constant.
// ---------------------------------------------------------------------------
__global__ void __launch_bounds__(256) k_vp(
                     const int* __restrict__ t,
                     const float* __restrict__ logits,
                     unsigned short* __restrict__ gpk,
                     int* __restrict__ hasfg_p,
                     float2* __restrict__ den,
                     float* __restrict__ out) {
    int tid = threadIdx.x;
    if (blockIdx.x >= VB_) {
        // ---- softmax-stats branch (float4: 4 pixels per thread) ----
        int pb = blockIdx.x - VB_;             // [0, 512)
        int b = pb >> 6;
        int p = ((pb & 63) << 10) + tid * 4;
        const float* lb = logits + (size_t)b * C_ * HW_ + p;
        float4 l[C_];
        float4 mx = make_float4(-3.4e38f, -3.4e38f, -3.4e38f, -3.4e38f);
        #pragma unroll
        for (int c = 0; c < C_; ++c) {
            l[c] = *(const float4*)(lb + (size_t)c * HW_);
            mx.x = fmaxf(mx.x, l[c].x);
            mx.y = fmaxf(mx.y, l[c].y);
            mx.z = fmaxf(mx.z, l[c].z);
            mx.w = fmaxf(mx.w, l[c].w);
        }
        float4 s = make_float4(0.f, 0.f, 0.f, 0.f);
        #pragma unroll
        for (int c = 0; c < C_; ++c) {
            s.x += __expf(l[c].x - mx.x);
            s.y += __expf(l[c].y - mx.y);
            s.z += __expf(l[c].z - mx.z);
            s.w += __expf(l[c].w - mx.w);
        }
        float2* dp = den + (size_t)b * HW_ + p;
        ((float4*)dp)[0] = make_float4(mx.x, 1.0f / s.x, mx.y, 1.0f / s.y);
        ((float4*)dp)[1] = make_float4(mx.z, 1.0f / s.z, mx.w, 1.0f / s.w);
        return;
    }

    // ---- vertical EDT branch: 2 adjacent columns per thread ----
    if (blockIdx.x == 0 && tid == 0) out[0] = 0.0f;   // replaces memset dispatch
    constexpr int SEG = 8, SH = 32;
    int s  = tid >> 5;          // segment
    int wl = tid & 31;          // column-pair within tile
    int blk = blockIdx.x;       // 96*4
    int bc = blk >> 2;
    int w0 = (blk & 3) * 64;
    int b = bc / C_, c = bc - b * C_;
    int w = w0 + 2 * wl;        // even
    const int* base = t + b * HW_ + w;
    int h0 = s * SH;

    // pass 1: load targets (int2 = 2 cols), pack to u8, per-segment stats
    unsigned tp0[SH / 4], tp1[SH / 4];
    int le0 = -1, ln0 = -1, fe0 = 256, fn0 = 256;
    int le1 = -1, ln1 = -1, fe1 = 256, fn1 = 256;
    #pragma unroll
    for (int i = 0; i < SH; ++i) {
        int2 tv = *(const int2*)(base + (h0 + i) * W_);
        if ((i & 3) == 0) { tp0[i >> 2] = 0; tp1[i >> 2] = 0; }
        tp0[i >> 2] |= (unsigned)tv.x << ((i & 3) * 8);
        tp1[i >> 2] |= (unsigned)tv.y << ((i & 3) * 8);
        int h = h0 + i;
        if (tv.x == c) { le0 = h; if (fe0 == 256) fe0 = h; }
        else           { ln0 = h; if (fn0 == 256) fn0 = h; }
        if (tv.y == c) { le1 = h; if (fe1 == 256) fe1 = h; }
        else           { ln1 = h; if (fn1 == 256) fn1 = h; }
    }
    __shared__ int sLE[SEG][64], sLN[SEG][64], sFE[SEG][64], sFN[SEG][64];
    sLE[s][2 * wl] = le0; sLE[s][2 * wl + 1] = le1;
    sLN[s][2 * wl] = ln0; sLN[s][2 * wl + 1] = ln1;
    sFE[s][2 * wl] = fe0; sFE[s][2 * wl + 1] = fe1;
    sFN[s][2 * wl] = fn0; sFN[s][2 * wl + 1] = fn1;
    __syncthreads();

    int carLE0 = -1, carLN0 = -1, carLE1 = -1, carLN1 = -1;
    for (int q = 0; q < s; ++q) {
        carLE0 = max(carLE0, sLE[q][2 * wl]);
        carLN0 = max(carLN0, sLN[q][2 * wl]);
        carLE1 = max(carLE1, sLE[q][2 * wl + 1]);
        carLN1 = max(carLN1, sLN[q][2 * wl + 1]);
    }
    int carFE0 = 256, carFN0 = 256, carFE1 = 256, carFN1 = 256;
    for (int q = s + 1; q < SEG; ++q) {
        carFE0 = min(carFE0, sFE[q][2 * wl]);
        carFN0 = min(carFN0, sFN[q][2 * wl]);
        carFE1 = min(carFE1, sFE[q][2 * wl + 1]);
        carFN1 = min(carFN1, sFN[q][2 * wl + 1]);
    }

    // block has-fg: wave 0, column = tid (64 columns)
    bool pred = false;
    if (tid < 64) {
        int m = -1;
        #pragma unroll
        for (int q = 0; q < SEG; ++q) m = max(m, sLE[q][tid]);
        pred = (m >= 0);
    }
    bool anyfg = __any(pred);
    if (tid == 0) hasfg_p[blk] = anyfg ? 1 : 0;

    // pass 2 (forward, carried): encode dl-1 as u8 (255 = no zero at-or-above)
    // relevant lastZ for a pixel is the OTHER type's last index (< h), so
    // dl = h - lastZ in [1,255] when valid -> dl-1 in [0,254]; 255 = invalid.
    unsigned ap0[SH / 4], ap1[SH / 4];
    {
        int l0 = carLE0, n0 = carLN0, l1 = carLE1, n1 = carLN1;
        #pragma unroll
        for (int i = 0; i < SH; ++i) {
            int h = h0 + i;
            int tv0 = (tp0[i >> 2] >> ((i & 3) * 8)) & 0xFF;
            int tv1 = (tp1[i >> 2] >> ((i & 3) * 8)) & 0xFF;
            int lz0, lz1;
            if (tv0 == c) { l0 = h; lz0 = n0; } else { n0 = h; lz0 = l0; }
            if (tv1 == c) { l1 = h; lz1 = n1; } else { n1 = h; lz1 = l1; }
            unsigned a0 = (lz0 < 0) ? 255u : (unsigned)(h - lz0 - 1);
            unsigned a1 = (lz1 < 0) ? 255u : (unsigned)(h - lz1 - 1);
            if ((i & 3) == 0) { ap0[i >> 2] = 0; ap1[i >> 2] = 0; }
            ap0[i >> 2] |= a0 << ((i & 3) * 8);
            ap1[i >> 2] |= a1 << ((i & 3) * 8);
        }
    }
    // pass 3 (backward, carried): d = min(dl, dn), write 2 cols as one u32
    {
        int fe0_ = carFE0, fn0_ = carFN0, fe1_ = carFE1, fn1_ = carFN1;
        unsigned* gk32 = (unsigned*)(gpk + (size_t)bc * HW_ + w);
        #pragma unroll
        for (int i = SH - 1; i >= 0; --i) {
            int h = h0 + i;
            int tv0 = (tp0[i >> 2] >> ((i & 3) * 8)) & 0xFF;
            int tv1 = (tp1[i >> 2] >> ((i & 3) * 8)) & 0xFF;
            int nz0, nz1; bool fg0, fg1;
            if (tv0 == c) { fe0_ = h; fg0 = true;  nz0 = fn0_; }
            else          { fn0_ = h; fg0 = false; nz0 = fe0_; }
            if (tv1 == c) { fe1_ = h; fg1 = true;  nz1 = fn1_; }
            else          { fn1_ = h; fg1 = false; nz1 = fe1_; }
            unsigned au0 = (ap0[i >> 2] >> ((i & 3) * 8)) & 0xFF;
            unsigned au1 = (ap1[i >> 2] >> ((i & 3) * 8)) & 0xFF;
            int dl0 = (au0 == 255u) ? 0x7FFF : (int)au0 + 1;
            int dl1 = (au1 == 255u) ? 0x7FFF : (int)au1 + 1;
            int dn0 = (nz0 > 255) ? 0x7FFF : (nz0 - h);
            int dn1 = (nz1 > 255) ? 0x7FFF : (nz1 - h);
            unsigned d0 = (unsigned)min(dl0, dn0) | (fg0 ? 0x8000u : 0u);
            unsigned d1 = (unsigned)min(dl1, dn1) | (fg1 ? 0x8000u : 0u);
            gk32[(h * W_) >> 1] = d0 | (d1 << 16);
        }
    }
}

// ---------------------------------------------------------------------------
// K2 (fused): per-row horizontal EDT + own-class prob + raw dice sums.
// One wave per (bc,h) row; 4 rows (same bc) per block; no dt materialized.
// LDS rows are wave-private -> no __syncthreads; a wave-local
// s_waitcnt lgkmcnt(0) orders the ds_writes before the scan's ds_reads.
// Prob-path globals (lrow/drow) hoisted above the scans to hide latency.
// ---------------------------------------------------------------------------
__global__ void __launch_bounds__(256) k_edt(
                      const unsigned short* __restrict__ gpk,
                      const float* __restrict__ logits,
                      const float2* __restrict__ den,
                      const int* __restrict__ hasfg_p,
                      float* __restrict__ part) {
    __shared__ float sp[4][W_ + 2 * PAD_];
    __shared__ float sn[4][W_ + 2 * PAD_];
    int wave = threadIdx.x >> 6;
    int lane = threadIdx.x & 63;
    int row = blockIdx.x * 4 + wave;       // bc*256 + h; all 4 rows same bc
    int bc = row >> 8;
    int b = bc / C_, c = bc - b * C_;
    int h = row & (H_ - 1);

    int hfl = 0;
    if (lane < 4) hfl = hasfg_p[bc * 4 + lane];
    bool hf = __any(hfl != 0);             // uniform across block (same bc)

    // hoist independent prob-path loads: latency hides under the EDT scans
    const float*  lrow = logits + ((size_t)b * C_ + c) * HW_ + h * W_;
    const float2* drow = den + (size_t)b * HW_ + h * W_;
    float lv[4]; float2 mv[4];
    #pragma unroll
    for (int i = 0; i < 4; ++i) {
        int j = lane + 64 * i;
        lv[i] = lrow[j];
        mv[i] = drow[j];
    }

    float dv[4];
    if (hf) {
        const ushort4 v4 = ((const ushort4*)(gpk + (size_t)row * W_))[lane];

        float4 inf4 = make_float4(3.0e38f, 3.0e38f, 3.0e38f, 3.0e38f);
        ((float4*)&sp[wave][0])[lane]          = inf4;
        ((float4*)&sp[wave][PAD_ + W_])[lane]  = inf4;
        ((float4*)&sn[wave][0])[lane]          = inf4;
        ((float4*)&sn[wave][PAD_ + W_])[lane]  = inf4;

        float s1 = (float)(1000000 - h);
        float sent2 = s1 * s1;             // == fl((1e6 - h)^2), reference-exact
        float4 fpv, fnv;
        {
            const unsigned short* vs = (const unsigned short*)&v4;
            float* fp = (float*)&fpv;
            float* fn = (float*)&fnv;
            #pragma unroll
            for (int q = 0; q < 4; ++q) {
                unsigned v = vs[q];
                unsigned d = v & 0x7FFFu;
                float g2 = (d == 0x7FFFu) ? sent2 : (float)(d * d);
                bool fg = (v & 0x8000u) != 0;
                fp[q] = fg ? g2 : 0.0f;
                fn[q] = fg ? 0.0f : g2;
            }
        }
        ((float4*)&sp[wave][PAD_])[lane] = fpv;
        ((float4*)&sn[wave][PAD_])[lane] = fnv;
        // wave-private LDS rows: wave-local wait is sufficient (no barrier)
        asm volatile("s_waitcnt lgkmcnt(0)" ::: "memory");

        float bp[4], bn[4];
        #pragma unroll
        for (int i = 0; i < 4; ++i) {
            int j = PAD_ + lane + 64 * i;
            bp[i] = sp[wave][j];
            bn[i] = sn[wave][j];
        }
        for (int r = 1; r < W_; ++r) {
            float fr = (float)r;
            float r2 = fr * fr;
            float m = fmaxf(fmaxf(bn[0], bn[1]), fmaxf(bn[2], bn[3]));
            if (!__any(r2 < m)) break;
            #pragma unroll
            for (int i = 0; i < 4; ++i) {
                int j = PAD_ + lane + 64 * i;
                float v = fminf(sn[wave][j - r], sn[wave][j + r]);
                bn[i] = fminf(bn[i], fmaf(fr, fr, v));
            }
        }
        for (int r = 1; r < W_; ++r) {
            float fr = (float)r;
            float r2 = fr * fr;
            float m = fmaxf(fmaxf(bp[0], bp[1]), fmaxf(bp[2], bp[3]));
            if (!__any(r2 < m)) break;
            #pragma unroll
            for (int i = 0; i < 4; ++i) {
                int j = PAD_ + lane + 64 * i;
                float v = fminf(sp[wave][j - r], sp[wave][j + r]);
                bp[i] = fminf(bp[i], fmaf(fr, fr, v));
            }
        }
        #pragma unroll
        for (int i = 0; i < 4; ++i) dv[i] = sqrtf(bn[i]) - sqrtf(bp[i]);
    } else {
        #pragma unroll
        for (int i = 0; i < 4; ++i) dv[i] = 0.0f;
    }

    // own-class prob from precomputed stats + raw sums over 256 pixels
    float s_pd = 0.f, s_p = 0.f, s_pp = 0.f, s_d = 0.f, s_dd = 0.f;
    float mn = 3.4e38f, mx = -3.4e38f;
    #pragma unroll
    for (int i = 0; i < 4; ++i) {
        float2 mi = mv[i];
        float pr = __expf(lv[i] - mi.x) * mi.y;
        float d = dv[i];
        s_pd = fmaf(pr, d, s_pd);
        s_p += pr;
        s_pp = fmaf(pr, pr, s_pp);
        s_d += d;
        s_dd = fmaf(d, d, s_dd);
        mn = fminf(mn, d);
        mx = fmaxf(mx, d);
    }
    #pragma unroll
    for (int off = 32; off; off >>= 1) {
        s_pd += __shfl_down(s_pd, off);
        s_p  += __shfl_down(s_p, off);
        s_pp += __shfl_down(s_pp, off);
        s_d  += __shfl_down(s_d, off);
        s_dd += __shfl_down(s_dd, off);
        mn = fminf(mn, __shfl_down(mn, off));
        mx = fmaxf(mx, __shfl_down(mx, off));
    }
    if (lane == 0) {
        float* p8 = part + (size_t)row * 8;
        p8[0] = s_pd; p8[1] = s_p; p8[2] = s_pp;
        p8[3] = s_d;  p8[4] = s_dd; p8[5] = mn; p8[6] = mx;
    }
}

// ---------------------------------------------------------------------------
// K3: per-(b,c) reduce of 256 row partials -> dice -> atomicAdd loss term.
// out[0] zeroed by k_vp block 0. inter = sc*(S_pd - mn*S_p);
// d2 = sc^2*(S_dd - 2 mn S_d + mn^2 N). 96 atomics total.
// ---------------------------------------------------------------------------
__global__ void __launch_bounds__(256) k_bcred(
                       const float* __restrict__ part, float* __restrict__ out) {
    int bc = blockIdx.x;
    int tid = threadIdx.x;                 // 256
    const float* p8 = part + ((size_t)bc * 256 + tid) * 8;
    float s_pd = p8[0], s_p = p8[1], s_pp = p8[2];
    float s_d = p8[3], s_dd = p8[4], mn = p8[5], mx = p8[6];
    #pragma unroll
    for (int off = 32; off; off >>= 1) {
        s_pd += __shfl_down(s_pd, off);
        s_p  += __shfl_down(s_p, off);
        s_pp += __shfl_down(s_pp, off);
        s_d  += __shfl_down(s_d, off);
        s_dd += __shfl_down(s_dd, off);
        mn = fminf(mn, __shfl_down(mn, off));
        mx = fmaxf(mx, __shfl_down(mx, off));
    }
    __shared__ float red[4][7];
    int wave = tid >> 6, lane = tid & 63;
    if (lane == 0) {
        red[wave][0] = s_pd; red[wave][1] = s_p; red[wave][2] = s_pp;
        red[wave][3] = s_d;  red[wave][4] = s_dd; red[wave][5] = mn; red[wave][6] = mx;
    }
    __syncthreads();
    if (tid == 0) {
        s_pd = red[0][0]; s_p = red[0][1]; s_pp = red[0][2];
        s_d = red[0][3]; s_dd = red[0][4]; mn = red[0][5]; mx = red[0][6];
        for (int w = 1; w < 4; ++w) {
            s_pd += red[w][0]; s_p += red[w][1]; s_pp += red[w][2];
            s_d += red[w][3]; s_dd += red[w][4];
            mn = fminf(mn, red[w][5]); mx = fmaxf(mx, red[w][6]);
        }
        float sc = 1.0f / (mx - mn + 1e-8f);
        float inter = sc * (s_pd - mn * s_p);
        float d2 = sc * sc * (s_dd - 2.0f * mn * s_d + mn * mn * (float)HW_);
        float dice = 2.0f * inter / (s_pp + d2 + 1e-6f);
        atomicAdd(out, (1.0f - dice) * (1.0f / (float)NBC_));
    }
}

// ---------------------------------------------------------------------------
extern "C" void kernel_launch(void* const* d_in, const int* in_sizes, int n_in,
                              void* d_out, int out_size, void* d_ws, size_t ws_size,
                              hipStream_t stream) {
    const float* logits  = (const float*)d_in[0];
    const int*   targets = (const int*)d_in[1];
    float* out = (float*)d_out;

    // ws layout: gpk u16[96*65536] | hasfg_p i32[768] | part f32[24576*8] |
    //            den float2[8*65536]   (hasfg_p uses only first 384 now)
    unsigned short* gpk = (unsigned short*)d_ws;
    int* hasfg_p = (int*)(gpk + (size_t)NBC_ * HW_);
    float* part = (float*)(hasfg_p + NBC_ * 8);
    float2* den = (float2*)(part + (size_t)NBC_ * H_ * 8);

    k_vp<<<VB_ + SMB_, 256, 0, stream>>>(targets, logits, gpk,
                                         hasfg_p, den, out);
    k_edt<<<NBC_ * H_ / 4, 256, 0, stream>>>(gpk, logits, den, hasfg_p, part);
    k_bcred<<<NBC_, 256, 0, stream>>>(part, out);
}